// Round 4
// baseline (256.277 us; speedup 1.0000x reference)
//
#include <hip/hip_runtime.h>
#include <math.h>

// R7: block-strip + 16-slot LDS window ring, reg-staged (T14), one
// __syncthreads per 4 rows. ZERO inline asm / global_load_lds — R6 bundled
// counted-vmcnt + raw s_barrier + global_load_lds and the container died
// twice; this round isolates the structural hypothesis with safe primitives.
//
// Hypothesis (R3/R4/R5 evidence): all prior structures sit at 82-91 us with
// HBM 31%, VALU <23%, zero LDS conflicts -> limiter is the 5x L1/L2-fill
// read amplification (671 MB fills in 82 us ~ 32 B/cy/CU) + per-row latency
// walls, not any throughput ceiling. The LDS ring cuts global reads to
// 1.125x; t-1/t-2/t-4 come from LDS as conflict-free ds_read_b128.
//
// Ring schedule (NSLOT=16 rows, 64 KB): slot(row r) = (r - t0 + 4) & 15.
// Iter i (of 8): computes rows t0+4i+wid reading slots [4i .. 4i+7];
// ds_writes staged row t0+4i+4+wid into slot 4i+8+wid (disjoint from this
// iter's reads); issues next stage load. Slot written at iter i was last
// read at iter i-2 -> the single end-of-iter barrier (two barriers between
// conflicting access) is sufficient. Stage load is issued one full iter
// before its ds_write -> HBM latency hides under compute.
// 1024 blocks, 2 blocks/CU (LDS-capped), 8 waves/CU. Each wave owns a full
// 1024-col row -> gate/scalar reduction stays intra-wave (no cross-wave LDS).

constexpr int T_DIM   = 4096;
constexpr int D_DIM   = 1024;
constexpr int L_STRIP = 32;              // rows per block
constexpr int NITER   = L_STRIP / 4;     // 8 iterations x 4 rows
constexpr int NSLOT   = 16;              // LDS ring slots (rows) = 64 KB

// ds_swizzle quad-perm broadcast patterns: offset[15]=1, offset[7:0]=2-bit sels
constexpr int QB0 = 0x8000;  // all quad lanes <- quad lane 0
constexpr int QB1 = 0x8055;  // all quad lanes <- quad lane 1
constexpr int QB2 = 0x80AA;  // all quad lanes <- quad lane 2

template <int PAT>
__device__ __forceinline__ float swz(float v) {
    return __int_as_float(__builtin_amdgcn_ds_swizzle(__float_as_int(v), PAT));
}

__device__ __forceinline__ float sigmoidf(float z) {
    return 1.0f / (1.0f + __expf(-z));
}

__global__ __launch_bounds__(256, 2) void clifford_kernel(
    const float* __restrict__ x,
    const float* __restrict__ gate_w,
    const float* __restrict__ gate_b,
    const float* __restrict__ scalar_w,
    const float* __restrict__ bivec_w,
    float* __restrict__ out,
    int nblocks)
{
    // XCD-aware swizzle: 1024 blocks (%8==0) -> 128 contiguous strips per
    // XCD = exactly one batch b per XCD; strip warm-up rows are L2-local.
    int blk = blockIdx.x;
    if ((gridDim.x & 7) == 0) {
        const int per = gridDim.x >> 3;
        blk = (blockIdx.x & 7) * per + (blockIdx.x >> 3);
    }

    const int tid  = threadIdx.x;
    const int wid  = tid >> 6;            // wave 0..3 owns rows t0 + 4i + wid
    const int lane = tid & 63;
    const int sub  = lane & 3;
    const int coff = lane << 2;           // float offset of this lane's float4

    const int spb = T_DIM / L_STRIP;      // strips per batch = 128
    const int b   = blk / spb;
    const int t0  = (blk - b * spb) * L_STRIP;

    const float* __restrict__ xb = x + (size_t)b * T_DIM * D_DIM;

    __shared__ float ring[NSLOT * D_DIM];     // 16 rows x 4 KB = 64 KB

    // ---- prologue: fill slots 0..7 = rows t0-4 .. t0+3 (2 rows per wave),
    //      plus first staged row (t0+4+wid) into regs ----
    float4 pa[4], pb[4], st[4], gv[4];
    {
        const int ra = (t0 - 4 + wid) & (T_DIM - 1);      // circular roll
        const int rb = t0 + wid;
        const float* ga = xb + (size_t)ra * D_DIM + coff;
        const float* gs = xb + (size_t)rb * D_DIM + coff;
        #pragma unroll
        for (int m = 0; m < 4; ++m) {
            pa[m] = *(const float4*)(ga + (m << 8));
            pb[m] = *(const float4*)(gs + (m << 8));
            gv[m] = *(const float4*)(gate_w + coff + (m << 8));
        }
        const float* g1 = xb + (size_t)(t0 + 4 + wid) * D_DIM + coff;
        #pragma unroll
        for (int m = 0; m < 4; ++m)
            st[m] = *(const float4*)(g1 + (m << 8));

        float* la = &ring[(wid)     * D_DIM] + coff;      // slot wid
        float* lb = &ring[(wid + 4) * D_DIM] + coff;      // slot wid+4
        #pragma unroll
        for (int m = 0; m < 4; ++m) {
            *(float4*)(la + (m << 8)) = pa[m];
            *(float4*)(lb + (m << 8)) = pb[m];
        }
    }

    const float ss = sigmoidf(scalar_w[0]);
    const float sb = sigmoidf(bivec_w[0]);
    const float gb = gate_b[0];

    // C0 diagonal signs for this lane's 4 blades (full table:
    // {1,1,1,-1, 1,-1,-1,-1, -1,1,1,1, 1,1,1,-1})
    float4 ws;
    if      (sub == 0) ws = make_float4( 1.f,  1.f,  1.f, -1.f);
    else if (sub == 1) ws = make_float4( 1.f, -1.f, -1.f, -1.f);
    else if (sub == 2) ws = make_float4(-1.f,  1.f,  1.f,  1.f);
    else               ws = make_float4( 1.f,  1.f,  1.f, -1.f);
    const float m3  = (sub == 0) ? 1.f : 0.f;   // elem3 <- k=3
    const float a1  = (sub == 1) ? 1.f : 0.f;   // elem1<-k=5, elem2<-k=6
    const float a2  = (sub == 2) ? 1.f : 0.f;   // elem1<-k=9, elem2<-k=10
    const float m12 = (sub == 3) ? 1.f : 0.f;   // elem0 <- k=12

    __syncthreads();    // prologue slots 0..7 visible to all waves

    #pragma unroll
    for (int i = 0; i < NITER; ++i) {
        // ---- 1) publish staged row (loaded last iter) for iter i+1 ----
        // write slots [4i+8 .. 4i+11] are disjoint (mod 16) from this
        // iter's read slots [4i .. 4i+7]; their previous readers were at
        // iter i-2, two barriers back.
        if (i + 1 < NITER) {
            float* l = &ring[((4 * i + 8 + wid) % NSLOT) * D_DIM] + coff;
            #pragma unroll
            for (int m = 0; m < 4; ++m)
                *(float4*)(l + (m << 8)) = st[m];   // ds_write_b128
        }
        // ---- 2) issue next stage load (consumed by iter i+1's ds_write) --
        if (i + 2 < NITER) {
            const float* g = xb + (size_t)(t0 + 4 * i + 8 + wid) * D_DIM + coff;
            #pragma unroll
            for (int m = 0; m < 4; ++m)
                st[m] = *(const float4*)(g + (m << 8));
        }

        // ---- 3) compute: wave wid owns row t0 + 4i + wid ----
        const int lq = 4 * i + wid + 4;
        const float* rc  = &ring[((lq)          % NSLOT) * D_DIM] + coff;
        const float* rp1 = &ring[((lq - 1)      % NSLOT) * D_DIM] + coff;
        const float* rp2 = &ring[((lq - 2)      % NSLOT) * D_DIM] + coff;
        const float* rp4 = &ring[((lq - 4)      % NSLOT) * D_DIM] + coff;

        float gp = 0.f, sc = 0.f;
        float4 xv[4], dl[4];

        #pragma unroll
        for (int m = 0; m < 4; ++m) {
            xv[m] = *(const float4*)(rc + (m << 8));        // ds_read_b128
            const float4 p1 = *(const float4*)(rp1 + (m << 8));
            const float4 p2 = *(const float4*)(rp2 + (m << 8));
            const float4 p4 = *(const float4*)(rp4 + (m << 8));
            const float4 cur = xv[m];

            float4 cs;  // csum = 3x - x[t-1] - x[t-2] - x[t-4]
            cs.x = 3.f * cur.x - p1.x - p2.x - p4.x;
            cs.y = 3.f * cur.y - p1.y - p2.y - p4.y;
            cs.z = 3.f * cur.z - p1.z - p2.z - p4.z;
            cs.w = 3.f * cur.w - p1.w - p2.w - p4.w;

            gp += cur.x * gv[m].x + cur.y * gv[m].y
                + cur.z * gv[m].z + cur.w * gv[m].w;
            sc += ws.x * (cur.x * cs.x) + ws.y * (cur.y * cs.y)
                + ws.z * (cur.z * cs.z) + ws.w * (cur.w * cs.w);

            // wedge: cross-blade values via quad broadcast (quad = 1 chunk)
            const float x1  = swz<QB0>(cur.y), x2  = swz<QB0>(cur.z);
            const float x4b = swz<QB1>(cur.x), x8b = swz<QB2>(cur.x);
            const float c1  = swz<QB0>(cs.y),  c2  = swz<QB0>(cs.z);
            const float c4b = swz<QB1>(cs.x),  c8b = swz<QB2>(cs.x);

            const float w3  = x1 * c2  - x2  * c1;    // k=3  (e12)
            const float w5  = x1 * c4b - x4b * c1;    // k=5  (e13)
            const float w6  = x2 * c4b - x4b * c2;    // k=6  (e23)
            const float w9  = x1 * c8b - x8b * c1;    // k=9  (e14)
            const float w10 = x2 * c8b - x8b * c2;    // k=10 (e24)
            const float w12 = x4b * c8b - x8b * c4b;  // k=12 (e34)

            dl[m] = make_float4(m12 * w12,
                                a1 * w5 + a2 * w9,
                                a1 * w6 + a2 * w10,
                                m3 * w3);
        }

        // intra-wave butterfly: full-row reduction (wave owns the whole row)
        #pragma unroll
        for (int o = 32; o > 0; o >>= 1) {
            gp += __shfl_xor(gp, o, 64);
            sc += __shfl_xor(sc, o, 64);
        }
        const float gate = sigmoidf(gp + gb);
        const float gsb  = gate * sb;

        const int t = t0 + 4 * i + wid;
        float* __restrict__ orow = out + ((size_t)b * T_DIM + t) * D_DIM + coff;
        #pragma unroll
        for (int m = 0; m < 4; ++m) {
            float4 o4;
            o4.x = xv[m].x + gsb * dl[m].x;
            o4.y = xv[m].y + gsb * dl[m].y;
            o4.z = xv[m].z + gsb * dl[m].z;
            o4.w = xv[m].w + gsb * dl[m].w;
            if (m == 0 && lane == 0) o4.x += gate * ss * sc;  // d==0
            *(float4*)(orow + (m << 8)) = o4;
        }

        // ---- 4) single barrier per iter: publishes this iter's ds_writes
        //      to iter i+1's readers; separates reads(i) from writes(i+2).
        __syncthreads();
    }
}

extern "C" void kernel_launch(void* const* d_in, const int* in_sizes, int n_in,
                              void* d_out, int out_size, void* d_ws, size_t ws_size,
                              hipStream_t stream) {
    const float* x  = (const float*)d_in[0];
    const float* gw = (const float*)d_in[1];
    const float* gb = (const float*)d_in[2];
    const float* sw = (const float*)d_in[3];
    const float* bw = (const float*)d_in[4];
    float* out = (float*)d_out;

    const int BT      = in_sizes[0] / D_DIM;     // 8*4096 = 32768 rows
    const int nblocks = BT / L_STRIP;            // 1024 blocks
    hipLaunchKernelGGL(clifford_kernel, dim3(nblocks), dim3(256), 0, stream,
                       x, gw, gb, sw, bw, out, nblocks);
}

// Round 5
// 239.764 us; speedup vs baseline: 1.0689x; 1.0689x over previous
//
#include <hip/hip_runtime.h>
#include <math.h>

// R8: one-shot block transaction. 4 rows per block; the 8 distinct input
// rows (t0-4..t0+3) staged to LDS via fire-and-forget global_load_lds
// (no VGPR dest -> compiler cannot serialize the loads through register
// pressure); ONE __syncthreads (the single vmcnt wall per block); compute
// entirely from LDS; store; die.
//
// Why: R3/R4/R5/R7 all exposed one memory wall per small work quantum
// (R3: compiler vmcnt(0) per m-iter, VGPR=48 proves the 20-load hoist was
// undone; R4/R7: __syncthreads == vmcnt(0)+lgkmcnt(0) drain per row/iter,
// which also drained stores and prefetches). Wave lifetime ~20k cy for
// ~2k cy of issue, all pipes <=30%. R8 has exactly one wall per block and
// 2.25x (vs 5x) L1/L2-fill read amplification.
// No inline asm, no raw barriers, no counted vmcnt (R6 lesson).

constexpr int T_DIM = 4096;
constexpr int D_DIM = 1024;
constexpr int NROW  = 4;                 // rows per block (1 per wave)
constexpr int NSLOT = 8;                 // staged rows t0-4 .. t0+3 = 32 KB

// ds_swizzle quad-perm broadcast patterns: offset[15]=1, offset[7:0]=2-bit sels
constexpr int QB0 = 0x8000;  // all quad lanes <- quad lane 0
constexpr int QB1 = 0x8055;  // all quad lanes <- quad lane 1
constexpr int QB2 = 0x80AA;  // all quad lanes <- quad lane 2

template <int PAT>
__device__ __forceinline__ float swz(float v) {
    return __int_as_float(__builtin_amdgcn_ds_swizzle(__float_as_int(v), PAT));
}

__device__ __forceinline__ float sigmoidf(float z) {
    return 1.0f / (1.0f + __expf(-z));
}

// async global->LDS, 16B/lane: LDS dest = wave-uniform base + lane*16,
// global src = per-lane address (lane l must read base + l*16 for a linear row)
__device__ __forceinline__ void gld16(const float* g, float* l) {
    __builtin_amdgcn_global_load_lds(
        (const __attribute__((address_space(1))) unsigned int*)g,
        (__attribute__((address_space(3))) unsigned int*)l,
        16, 0, 0);
}

__global__ __launch_bounds__(256, 4) void clifford_kernel(
    const float* __restrict__ x,
    const float* __restrict__ gate_w,
    const float* __restrict__ gate_b,
    const float* __restrict__ scalar_w,
    const float* __restrict__ bivec_w,
    float* __restrict__ out,
    int nblocks)
{
    // XCD-aware swizzle: 8192 blocks (%8==0) -> 1024 contiguous blocks per
    // XCD = exactly one batch b per XCD; neighbor blocks share 4 of 8 input
    // rows -> those re-reads are same-XCD L2 hits.
    int blk = blockIdx.x;
    if ((gridDim.x & 7) == 0) {
        const int per = gridDim.x >> 3;
        blk = (blockIdx.x & 7) * per + (blockIdx.x >> 3);
    }
    if (blk >= nblocks) return;

    const int tid  = threadIdx.x;
    const int wid  = tid >> 6;            // wave w computes row t0 + w
    const int lane = tid & 63;
    const int sub  = lane & 3;
    const int coff = lane << 2;           // float offset of this lane's float4

    const int rpb = T_DIM / NROW;         // row-groups per batch = 1024
    const int b   = blk / rpb;
    const int t0  = (blk - b * rpb) * NROW;

    const float* __restrict__ xb = x + (size_t)b * T_DIM * D_DIM;

    __shared__ float ring[NSLOT * D_DIM];     // 8 rows x 4 KB = 32 KB

    // ---- stage slots 0..7 = rows t0-4 .. t0+3 (wave w does slots w, w+4).
    // 8 gld16-instruction groups, all in flight; no VGPR round-trip. ----
    #pragma unroll
    for (int p = 0; p < 2; ++p) {
        const int q    = p * 4 + wid;                    // slot 0..7
        const int trow = (t0 + q - 4) & (T_DIM - 1);     // circular == jnp.roll
        const float* g = xb + (size_t)trow * D_DIM + coff;
        float* l       = &ring[q * D_DIM];               // wave-uniform base
        #pragma unroll
        for (int m = 0; m < 4; ++m)
            gld16(g + (m << 8), l + (m << 8));
    }

    // gate weights as plain VGPR loads (drained by the same single wall)
    float4 gv[4];
    #pragma unroll
    for (int m = 0; m < 4; ++m)
        gv[m] = *(const float4*)(gate_w + coff + (m << 8));

    const float ss = sigmoidf(scalar_w[0]);
    const float sb = sigmoidf(bivec_w[0]);
    const float gb = gate_b[0];

    // C0 diagonal signs for this lane's 4 blades (full table:
    // {1,1,1,-1, 1,-1,-1,-1, -1,1,1,1, 1,1,1,-1})
    float4 ws;
    if      (sub == 0) ws = make_float4( 1.f,  1.f,  1.f, -1.f);
    else if (sub == 1) ws = make_float4( 1.f, -1.f, -1.f, -1.f);
    else if (sub == 2) ws = make_float4(-1.f,  1.f,  1.f,  1.f);
    else               ws = make_float4( 1.f,  1.f,  1.f, -1.f);
    const float m3  = (sub == 0) ? 1.f : 0.f;   // elem3 <- k=3
    const float a1  = (sub == 1) ? 1.f : 0.f;   // elem1<-k=5, elem2<-k=6
    const float a2  = (sub == 2) ? 1.f : 0.f;   // elem1<-k=9, elem2<-k=10
    const float m12 = (sub == 3) ? 1.f : 0.f;   // elem0 <- k=12

    __syncthreads();   // THE single wall: drains gld16s + gv, then barrier

    // ---- compute: wave wid owns row t0 + wid, entirely from LDS ----
    const int lq = wid + 4;                          // slot of cur row
    const float* rc  = &ring[(lq)     * D_DIM] + coff;
    const float* rp1 = &ring[(lq - 1) * D_DIM] + coff;
    const float* rp2 = &ring[(lq - 2) * D_DIM] + coff;
    const float* rp4 = &ring[(lq - 4) * D_DIM] + coff;

    float gp = 0.f, sc = 0.f;
    float4 xv[4], dl[4];

    #pragma unroll
    for (int m = 0; m < 4; ++m) {
        xv[m] = *(const float4*)(rc + (m << 8));        // ds_read_b128
        const float4 p1 = *(const float4*)(rp1 + (m << 8));
        const float4 p2 = *(const float4*)(rp2 + (m << 8));
        const float4 p4 = *(const float4*)(rp4 + (m << 8));
        const float4 cur = xv[m];

        float4 cs;  // csum = 3x - x[t-1] - x[t-2] - x[t-4]
        cs.x = 3.f * cur.x - p1.x - p2.x - p4.x;
        cs.y = 3.f * cur.y - p1.y - p2.y - p4.y;
        cs.z = 3.f * cur.z - p1.z - p2.z - p4.z;
        cs.w = 3.f * cur.w - p1.w - p2.w - p4.w;

        gp += cur.x * gv[m].x + cur.y * gv[m].y
            + cur.z * gv[m].z + cur.w * gv[m].w;
        sc += ws.x * (cur.x * cs.x) + ws.y * (cur.y * cs.y)
            + ws.z * (cur.z * cs.z) + ws.w * (cur.w * cs.w);

        // wedge: cross-blade values via quad broadcast (quad = 1 chunk)
        const float x1  = swz<QB0>(cur.y), x2  = swz<QB0>(cur.z);
        const float x4b = swz<QB1>(cur.x), x8b = swz<QB2>(cur.x);
        const float c1  = swz<QB0>(cs.y),  c2  = swz<QB0>(cs.z);
        const float c4b = swz<QB1>(cs.x),  c8b = swz<QB2>(cs.x);

        const float w3  = x1 * c2  - x2  * c1;    // k=3  (e12)
        const float w5  = x1 * c4b - x4b * c1;    // k=5  (e13)
        const float w6  = x2 * c4b - x4b * c2;    // k=6  (e23)
        const float w9  = x1 * c8b - x8b * c1;    // k=9  (e14)
        const float w10 = x2 * c8b - x8b * c2;    // k=10 (e24)
        const float w12 = x4b * c8b - x8b * c4b;  // k=12 (e34)

        dl[m] = make_float4(m12 * w12,
                            a1 * w5 + a2 * w9,
                            a1 * w6 + a2 * w10,
                            m3 * w3);
    }

    // intra-wave butterfly: full-row reduction (wave owns the whole row)
    #pragma unroll
    for (int o = 32; o > 0; o >>= 1) {
        gp += __shfl_xor(gp, o, 64);
        sc += __shfl_xor(sc, o, 64);
    }
    const float gate = sigmoidf(gp + gb);
    const float gsb  = gate * sb;

    const int t = t0 + wid;
    float* __restrict__ orow = out + ((size_t)b * T_DIM + t) * D_DIM + coff;
    #pragma unroll
    for (int m = 0; m < 4; ++m) {
        float4 o4;
        o4.x = xv[m].x + gsb * dl[m].x;
        o4.y = xv[m].y + gsb * dl[m].y;
        o4.z = xv[m].z + gsb * dl[m].z;
        o4.w = xv[m].w + gsb * dl[m].w;
        if (m == 0 && lane == 0) o4.x += gate * ss * sc;  // d==0
        *(float4*)(orow + (m << 8)) = o4;
    }
    // no trailing barrier: stores fire and the wave retires
}

extern "C" void kernel_launch(void* const* d_in, const int* in_sizes, int n_in,
                              void* d_out, int out_size, void* d_ws, size_t ws_size,
                              hipStream_t stream) {
    const float* x  = (const float*)d_in[0];
    const float* gw = (const float*)d_in[1];
    const float* gb = (const float*)d_in[2];
    const float* sw = (const float*)d_in[3];
    const float* bw = (const float*)d_in[4];
    float* out = (float*)d_out;

    const int BT      = in_sizes[0] / D_DIM;     // 8*4096 = 32768 rows
    const int nblocks = BT / NROW;               // 8192 blocks
    hipLaunchKernelGGL(clifford_kernel, dim3(nblocks), dim3(256), 0, stream,
                       x, gw, gb, sw, bw, out, nblocks);
}